// Round 19
// baseline (807.135 us; speedup 1.0000x reference)
//
#include <hip/hip_runtime.h>

#define T_STEPS 10000
#define BATCH   512

__device__ __forceinline__ float fexp2(float x) {
#if __has_builtin(__builtin_amdgcn_exp2f)
  return __builtin_amdgcn_exp2f(x);
#else
  return exp2f(x);
#endif
}

__device__ __forceinline__ float frcp(float x) {
#if __has_builtin(__builtin_amdgcn_rcpf)
  return __builtin_amdgcn_rcpf(x);
#else
  return 1.0f / x;
#endif
}

// Pin: force value into a VGPR here (blocks load-sinking; R11-validated).
#define PIN(x) asm volatile("" : "+v"(x))

// Quad-local permute: lane j of each quad receives from lane sel_j.
template <int CTRL>
__device__ __forceinline__ float qperm(float v) {
  int i = __builtin_bit_cast(int, v);
#if __has_builtin(__builtin_amdgcn_mov_dpp)
  int r = __builtin_amdgcn_mov_dpp(i, CTRL, 0xF, 0xF, true);
#else
  int r = __builtin_amdgcn_ds_swizzle(i, 0x8000 | CTRL);
#endif
  return __builtin_bit_cast(float, r);
}

// Roles in a quad (b = tid>>2, role = tid&3):
//  r0: f_W/c_W | r1: f_N/c_N | r2: f_R/c_R | r3: h/0
// Scheme (validated R4-R17, absmax pinned at exact kernel's 0.0039):
//  * main sigmoid frozen per step, extrapolated coupling m = x + EXT*d
//  * c-sigmoid affine, 16-step refresh, P folded, KG folded
//  * RK4 step in closed affine form (basis-extracted coefficients)
//  * 8-step groups, 8-wide exp/rcp batches; conflict-free LDS staging
//  * triple-buffered noise + PIN; coalesced wide flush (R17)
// New in R19 (R18 done right): ping-pong LDS halves; flush the PREVIOUS
// half at block TOP: reads see lgkmcnt~0 (its writes completed a whole
// block ago), read latency hides under the 16 noise-load issues, stores
// fire immediately after. vv liveness spans only the load section (no
// GROUP8 crossing -> no R18 VGPR blowup), no scheduling fence.
__global__ __launch_bounds__(64, 1)
void sleep_rk4_kernel(const float* __restrict__ noise,
                      const float* __restrict__ pgRRe,
                      const float* __restrict__ pgRWe,
                      const float* __restrict__ pgWNi,
                      const float* __restrict__ pgWRi,
                      const float* __restrict__ pgNRi,
                      const float* __restrict__ pgNWi,
                      float* __restrict__ out)
{
  __shared__ float shm[2 * 2048];   // two halves of [16 steps][8 regions x 16]

  const int tid  = (int)(blockIdx.x * 64u + threadIdx.x);
  const int b    = tid >> 2;        // global element
  const int bl   = b & 15;          // element within block
  const int role = tid & 3;

  const float g_RRe = *pgRRe, g_RWe = *pgRWe, g_WNi = *pgWNi;
  const float g_WRi = *pgWRi, g_NRi = *pgNRi, g_NWi = *pgNWi;

  const float L2E = 1.4426950408889634f;
  const float LN2 = 0.6931471805599453f;

  float W1, W2, W3, NSC, BB, qa, qb, pa, pb, cs, ia, ib;
  float f0, c0;
  bool role03;

  if (role == 0) {              // f_W / c_W
    const float SC = 2.0f * L2E / 0.5f;
    W1 = SC * g_NWi; W2 = SC * g_RWe; W3 = 0.0f; NSC = SC; BB = SC * 0.4f;
    qa = -1.0f / 1.5e6f; qb = 6.5f / 1.5e6f; pa = 0.0f; pb = -6.5f / 1.5e6f;
    cs = 2.0f * L2E / 5.0f; ia = -1.0f / 2.5e4f; ib = 1.0f / 2.5e4f;
    f0 = 6.0f; c0 = 0.9f; role03 = true;
  } else if (role == 1) {       // f_N / c_N
    const float SC = 2.0f * L2E / 0.175f;
    W1 = SC * g_WNi; W2 = SC * 1.5f; W3 = 0.0f; NSC = SC; BB = 0.0f;
    qa = -1.0f / 6.0e5f; qb = 5.0f / 6.0e5f; pa = 0.0f; pb = -5.0f / 6.0e5f;
    cs = 2.0f * L2E / 4.0f; ia = -1.0f / 1.0e4f; ib = 1.0f / 1.0e4f;
    f0 = 1.0e-3f; c0 = 1.0e-3f; role03 = false;
  } else if (role == 2) {       // f_R / c_R
    const float SC = 2.0f * L2E / 0.13f;
    W1 = SC * g_WRi; W2 = SC * g_NRi; W3 = SC * g_RRe; NSC = SC; BB = SC * 0.9f;
    qa = -1.0f / 6.0e4f; qb = 5.0f / 6.0e4f; pa = 0.0f; pb = -5.0f / 6.0e4f;
    cs = 2.0f * L2E / 2.0f; ia = -1.0f / 1.0e4f; ib = 1.0f / 1.0e4f;
    f0 = 1.0e-3f; c0 = 1.0e-3f; role03 = false;
  } else {                      // h (c-chain inert: stays 0, goes to trash)
    W1 = 0.0f; W2 = -5.0f * L2E; W3 = 0.0f; NSC = 0.0f; BB = 10.0f * L2E;
    qa = -1.0f / 3.06e7f; qb = 0.0f;
    pa = (1.0f / 3.06e7f - 1.0f / 3.483e7f);
    pb = 1.0f / 3.483e7f;
    cs = 0.0f; ia = 0.0f; ib = 0.0f;
    f0 = 0.5f; c0 = 0.0f; role03 = true;
  }

  const float AQAh = 0.5f * qa, AQA1 = qa;
  const float AIAh = 0.5f * ia, AIA1 = ia;
  const float IAC  = ia * cs;
  const float TIA  = 2.0f * ia;
  const float R6   = 0.16666666666666666f;

  // ---- init: closed-form step coefficients via basis runs ----
  float vF[4], vG[4];
  auto frun = [&](float f0b, float Gb, float* v) -> float {
    const float Chb = fmaf(0.5f, Gb, f0b), C1b = f0b + Gb;
    float s0 = f0b, acc = -3.0f * f0b;
    s0 = fmaf(AQAh, s0, Chb); v[0] = s0; acc = fmaf(2.0f, s0, acc);
    s0 = fmaf(AQAh, s0, Chb); v[1] = s0; acc = fmaf(4.0f, s0, acc);
    s0 = fmaf(AQA1, s0, C1b); v[2] = s0; acc = fmaf(2.0f, s0, acc);
    s0 = fmaf(AQA1, s0, C1b); v[3] = s0; acc = fmaf(1.0f, s0, acc);
    float q = acc * R6; q = fmaf(fmaf(q, -6.0f, acc), R6, q); return q;
  };
  const float KF = frun(1.0f, 0.0f, vF);
  const float KG = frun(0.0f, 1.0f, vG);

  auto crun = [&](const float* v, float c0b, float e1u, float vd1) -> float {
    const float E1h = IAC * e1u, E11 = 2.0f * IAC * e1u;
    const float Dh = c0b + 0.5f * vd1, D1 = c0b + vd1;
    float s1 = c0b, acc = -3.0f * c0b;
    s1 = fmaf(AIAh, s1, fmaf(E1h, v[0], Dh)); acc = fmaf(2.0f, s1, acc);
    s1 = fmaf(AIAh, s1, fmaf(E1h, v[1], Dh)); acc = fmaf(4.0f, s1, acc);
    s1 = fmaf(AIA1, s1, fmaf(E11, v[2], D1)); acc = fmaf(2.0f, s1, acc);
    s1 = fmaf(AIA1, s1, fmaf(E11, v[3], D1)); acc = fmaf(1.0f, s1, acc);
    float q = acc * R6; q = fmaf(fmaf(q, -6.0f, acc), R6, q); return q;
  };
  float z4[4] = {0.0f, 0.0f, 0.0f, 0.0f};
  const float KC  = crun(z4, 1.0f, 0.0f, 0.0f);
  const float LAf = crun(vF, 0.0f, 1.0f, 0.0f);
  const float LBf = crun(vG, 0.0f, 1.0f, 0.0f);
  const float KW  = crun(z4, 0.0f, 0.0f, 1.0f);

  // KG-folded constants (ulp-level identical numerics)
  const float KGi  = 1.0f / KG;
  const float LBfK = LBf * KGi;
  const float qbK  = qb * KG;

  // ---- c-sigmoid + P refresh (16-step cadence; compute/install split) ----
  float LAe, LBK, VDK, PK, tLAe, tLBK, tVDK, tPK;
  auto crefresh_compute = [&](float fcur) {
    const float zb = cs * fcur;
    const float ez = fexp2(zb);
    const float sc_ = frcp(1.0f + ez);
    const float t2 = fmaf(sc_, sc_, -sc_);
    const float e1 = LN2 * t2;
    const float vC = fmaf(-e1, zb, sc_);
    const float VD1 = fmaf(TIA, vC, ib);
    tLAe = LAf * e1; tLBK = LBfK * e1; tVDK = KW * VD1;
    tPK = fmaf(pa, fcur, pb) * KG;
  };
  crefresh_compute(f0);
  LAe = tLAe; LBK = tLBK; VDK = tVDK; PK = tPK;

  float dF = 0.0f, dC = 0.0f;
  float Gq0, Gq1, Gq2, Gq3, Gq4, Gq5, Gq6, Gq7;   // = KG * G (folded)

  // ---- LDS staging addresses (bank-conflict-free regions) ----
  const int offA = role * 16 + bl;          // f -> region[role]
  const int offB = (role + 4) * 16 + bl;    // c -> region[4+role] (r3 -> trash)

  // ---- coalesced flush setup (per-lane constants) ----
  const int  L        = (int)threadIdx.x;
  const bool fluseful = ((L & 31) < 28);
  float* gp;
  {
    const int p  = L & 31;          // unit within 32-unit step row
    const int rg = p >> 2;          // region 0..7 (7 = trash, masked)
    const int v  = (rg == 3) ? 6 : ((rg < 3) ? rg : (rg > 6 ? 0 : rg - 1));
    gp = out + (L >> 5) * 3584 + v * 512 + (p & 3) * 4 + (int)(blockIdx.x * 16u);
  }

  float nbA[16], nbB[16], nbCv[16];
#pragma unroll
  for (int j = 0; j < 16; ++j) nbA[j] = noise[b + j * BATCH];
#pragma unroll
  for (int j = 0; j < 16; ++j) nbB[j] = noise[b + (16 + j) * BATCH];

  // ---- prefill: GK for steps 0..7 (frozen state, zero slope) ----
  {
    const float pubS = role03 ? f0 : c0;
    const float xAs = qperm<0x01>(c0);
    const float xBs = qperm<0x1E>(pubS);
    const float YB = fmaf(W1, xAs, fmaf(W2, xBs, fmaf(W3, c0, BB)));
    Gq0 = fmaf(PK, frcp(1.0f + fexp2(fmaf(NSC, nbA[0], YB))), qbK);
    Gq1 = fmaf(PK, frcp(1.0f + fexp2(fmaf(NSC, nbA[1], YB))), qbK);
    Gq2 = fmaf(PK, frcp(1.0f + fexp2(fmaf(NSC, nbA[2], YB))), qbK);
    Gq3 = fmaf(PK, frcp(1.0f + fexp2(fmaf(NSC, nbA[3], YB))), qbK);
    Gq4 = fmaf(PK, frcp(1.0f + fexp2(fmaf(NSC, nbA[4], YB))), qbK);
    Gq5 = fmaf(PK, frcp(1.0f + fexp2(fmaf(NSC, nbA[5], YB))), qbK);
    Gq6 = fmaf(PK, frcp(1.0f + fexp2(fmaf(NSC, nbA[6], YB))), qbK);
    Gq7 = fmaf(PK, frcp(1.0f + fexp2(fmaf(NSC, nbA[7], YB))), qbK);
  }

  // One 8-step group staging at literal LDS base SB: consumes Gq0..7,
  // computes next group's GK batch (EXT = 8.5..15.5), 8 step-maps.
  auto GROUP8 = [&](int SB, float n0, float n1, float n2, float n3,
                    float n4, float n5, float n6, float n7) {
    const float pubS = role03 ? f0 : c0;
    const float pubD = role03 ? dF : dC;
    const float xAs = qperm<0x01>(c0);
    const float xBs = qperm<0x1E>(pubS);
    const float xAd = qperm<0x01>(dC);
    const float xBd = qperm<0x1E>(pubD);
    float YB = fmaf(W3, c0, BB);
    float dY = W3 * dC;
    const float f1 = fmaf(KF, f0, Gq0);
    const float c1 = fmaf(KC, c0, fmaf(LAe, f0, fmaf(LBK, Gq0, VDK)));
    YB = fmaf(W2, xBs, YB);
    dY = fmaf(W2, xBd, dY);
    const float f2 = fmaf(KF, f1, Gq1);
    const float c2 = fmaf(KC, c1, fmaf(LAe, f1, fmaf(LBK, Gq1, VDK)));
    YB = fmaf(W1, xAs, YB);
    dY = fmaf(W1, xAd, dY);
    const float f3 = fmaf(KF, f2, Gq2);
    const float c3 = fmaf(KC, c2, fmaf(LAe, f2, fmaf(LBK, Gq2, VDK)));
    const float y0 = fmaf(NSC, n0, fmaf( 8.5f, dY, YB));
    const float y1 = fmaf(NSC, n1, fmaf( 9.5f, dY, YB));
    const float y2 = fmaf(NSC, n2, fmaf(10.5f, dY, YB));
    const float y3 = fmaf(NSC, n3, fmaf(11.5f, dY, YB));
    const float f4 = fmaf(KF, f3, Gq3);
    const float c4 = fmaf(KC, c3, fmaf(LAe, f3, fmaf(LBK, Gq3, VDK)));
    const float y4 = fmaf(NSC, n4, fmaf(12.5f, dY, YB));
    const float y5 = fmaf(NSC, n5, fmaf(13.5f, dY, YB));
    const float y6 = fmaf(NSC, n6, fmaf(14.5f, dY, YB));
    const float y7 = fmaf(NSC, n7, fmaf(15.5f, dY, YB));
    const float e0 = fexp2(y0);
    const float e1_ = fexp2(y1);
    const float f5 = fmaf(KF, f4, Gq4);
    const float c5 = fmaf(KC, c4, fmaf(LAe, f4, fmaf(LBK, Gq4, VDK)));
    const float e2 = fexp2(y2);
    const float e3 = fexp2(y3);
    const float f6 = fmaf(KF, f5, Gq5);
    const float c6 = fmaf(KC, c5, fmaf(LAe, f5, fmaf(LBK, Gq5, VDK)));
    const float e4 = fexp2(y4);
    const float e5 = fexp2(y5);
    const float f7 = fmaf(KF, f6, Gq6);
    const float c7 = fmaf(KC, c6, fmaf(LAe, f6, fmaf(LBK, Gq6, VDK)));
    const float e6 = fexp2(y6);
    const float e7 = fexp2(y7);
    const float f8 = fmaf(KF, f7, Gq7);
    const float c8 = fmaf(KC, c7, fmaf(LAe, f7, fmaf(LBK, Gq7, VDK)));
    const float r0 = frcp(1.0f + e0);
    const float r1 = frcp(1.0f + e1_);
    const float r2 = frcp(1.0f + e2);
    const float r3 = frcp(1.0f + e3);
    const float r4 = frcp(1.0f + e4);
    const float r5 = frcp(1.0f + e5);
    const float r6 = frcp(1.0f + e6);
    const float r7 = frcp(1.0f + e7);
    shm[SB + 0 * 128 + offA] = f1;  shm[SB + 0 * 128 + offB] = c1;
    shm[SB + 1 * 128 + offA] = f2;  shm[SB + 1 * 128 + offB] = c2;
    shm[SB + 2 * 128 + offA] = f3;  shm[SB + 2 * 128 + offB] = c3;
    shm[SB + 3 * 128 + offA] = f4;  shm[SB + 3 * 128 + offB] = c4;
    shm[SB + 4 * 128 + offA] = f5;  shm[SB + 4 * 128 + offB] = c5;
    shm[SB + 5 * 128 + offA] = f6;  shm[SB + 5 * 128 + offB] = c6;
    shm[SB + 6 * 128 + offA] = f7;  shm[SB + 6 * 128 + offB] = c7;
    shm[SB + 7 * 128 + offA] = f8;  shm[SB + 7 * 128 + offB] = c8;
    Gq0 = fmaf(PK, r0, qbK);
    Gq1 = fmaf(PK, r1, qbK);
    Gq2 = fmaf(PK, r2, qbK);
    Gq3 = fmaf(PK, r3, qbK);
    Gq4 = fmaf(PK, r4, qbK);
    Gq5 = fmaf(PK, r5, qbK);
    Gq6 = fmaf(PK, r6, qbK);
    Gq7 = fmaf(PK, r7, qbK);
    dF = f8 - f7; dC = c8 - c7;
    f0 = f8; c0 = c8;
  };

  int base = 0;

  // 16-step block, triple-buffered noise, PH = LDS half (literal 0/1),
  // FL = flush-enable (literal). Flush of half PH^1 (staged LAST block,
  // writes long complete -> lgkmcnt~0) sits at block TOP: reads, then the
  // 16 noise loads (hide read latency), then stores. vv liveness ends
  // before GROUP8#1 -> no register-pressure blowup (R18's failure mode).
#define TBLOCK(nb1_, nb2_, nbL_, PH, FL)                                      \
  do {                                                                        \
    int tl = base + 32; if (tl > T_STEPS - 16) tl = T_STEPS - 16;             \
    const float* __restrict__ lp = noise + (size_t)tl * BATCH;                \
    float4 vv[8];                                                             \
    if (FL && fluseful) {                                                     \
      _Pragma("unroll")                                                       \
      for (int r = 0; r < 8; ++r)                                             \
        vv[r] = *(const float4*)&shm[(PH ^ 1) * 2048 + L * 4 + r * 256];      \
    }                                                                         \
    _Pragma("unroll")                                                         \
    for (int j = 0; j < 16; ++j) nbL_[j] = lp[b + j * BATCH];                 \
    if (FL && fluseful) {                                                     \
      _Pragma("unroll")                                                       \
      for (int r = 0; r < 8; ++r) { *(float4*)gp = vv[r]; gp += 7168; }       \
    }                                                                         \
    _Pragma("unroll")                                                         \
    for (int j = 8; j < 16; ++j) PIN(nb1_[j]);                                \
    _Pragma("unroll")                                                         \
    for (int j = 0; j < 8; ++j) PIN(nb2_[j]);                                 \
    crefresh_compute(f0);                                                     \
    GROUP8((PH) * 2048 + 0, nb1_[8], nb1_[9], nb1_[10], nb1_[11],             \
              nb1_[12], nb1_[13], nb1_[14], nb1_[15]);                        \
    LAe = tLAe; LBK = tLBK; VDK = tVDK; PK = tPK;                             \
    GROUP8((PH) * 2048 + 1024, nb2_[0], nb2_[1], nb2_[2], nb2_[3],            \
              nb2_[4], nb2_[5], nb2_[6], nb2_[7]);                            \
    base += 16;                                                               \
  } while (0)

  // 625 blocks: block0 (no flush, stages half0) + 104 x 6-block period
  // (each flushes the previous block's half) + epilogue flush of half0.
  TBLOCK(nbA, nbB, nbCv, 0, 0);
  for (int kk = 0; kk < 104; ++kk) {
    TBLOCK(nbB, nbCv, nbA, 1, 1);
    TBLOCK(nbCv, nbA, nbB, 0, 1);
    TBLOCK(nbA, nbB, nbCv, 1, 1);
    TBLOCK(nbB, nbCv, nbA, 0, 1);
    TBLOCK(nbCv, nbA, nbB, 1, 1);
    TBLOCK(nbA, nbB, nbCv, 0, 1);
  }
#undef TBLOCK
  // epilogue: flush block 624's half (PH=0)
  if (fluseful) {
#pragma unroll
    for (int r = 0; r < 8; ++r) {
      const float4 vv = *(const float4*)&shm[0 + L * 4 + r * 256];
      *(float4*)gp = vv;
      gp += 7168;
    }
  }
}

extern "C" void kernel_launch(void* const* d_in, const int* in_sizes, int n_in,
                              void* d_out, int out_size, void* d_ws, size_t ws_size,
                              hipStream_t stream) {
  const float* noise = (const float*)d_in[0];
  const float* gRRe  = (const float*)d_in[1];
  const float* gRWe  = (const float*)d_in[2];
  const float* gWNi  = (const float*)d_in[3];
  const float* gWRi  = (const float*)d_in[4];
  const float* gNRi  = (const float*)d_in[5];
  const float* gNWi  = (const float*)d_in[6];
  float* out = (float*)d_out;

  // 32 blocks x 64 threads -> 1 wave/CU on 32 CUs (max TLP for B=512@4 lanes).
  sleep_rk4_kernel<<<dim3((BATCH * 4) / 64), dim3(64), 0, stream>>>(
      noise, gRRe, gRWe, gWNi, gWRi, gNRi, gNWi, out);
}

// Round 20
// 464.457 us; speedup vs baseline: 1.7378x; 1.7378x over previous
//
#include <hip/hip_runtime.h>

#define T_STEPS 10000
#define BATCH   512

__device__ __forceinline__ float fexp2(float x) {
#if __has_builtin(__builtin_amdgcn_exp2f)
  return __builtin_amdgcn_exp2f(x);
#else
  return exp2f(x);
#endif
}

__device__ __forceinline__ float frcp(float x) {
#if __has_builtin(__builtin_amdgcn_rcpf)
  return __builtin_amdgcn_rcpf(x);
#else
  return 1.0f / x;
#endif
}

// Pin: force value into a VGPR here (blocks load-sinking; R11-validated).
#define PIN(x) asm volatile("" : "+v"(x))

// Quad-local permute: lane j of each quad receives from lane sel_j.
template <int CTRL>
__device__ __forceinline__ float qperm(float v) {
  int i = __builtin_bit_cast(int, v);
#if __has_builtin(__builtin_amdgcn_mov_dpp)
  int r = __builtin_amdgcn_mov_dpp(i, CTRL, 0xF, 0xF, true);
#else
  int r = __builtin_amdgcn_ds_swizzle(i, 0x8000 | CTRL);
#endif
  return __builtin_bit_cast(float, r);
}

// Roles in a quad (b = tid>>2, role = tid&3):
//  r0: f_W/c_W | r1: f_N/c_N | r2: f_R/c_R | r3: h/0
// Scheme (validated R4-R16, absmax pinned at exact kernel's 0.0039):
//  * main sigmoid frozen per step, extrapolated coupling m = x + EXT*d
//  * c-sigmoid affine, 16-step refresh, P folded, KG folded
//  * RK4 step in closed affine form (basis-extracted coefficients)
//  * 8-step groups, 8-wide exp/rcp batches (R16)
//  * LDS-staged output, conflict-free region layout (R16)
// R17 (best, 465us): triple-buffered noise (24 vmem ops/block -> 2-block
// prefetch distance vmcnt-encodable) + coalesced flush (lane L reads shm
// bytes L*16+r*1024, conflict-free b128; per-lane-constant out scatter).
// R18/R19 (flush-at-top pipelining) both REGRESSED via VGPR/schedule
// side-effects -> this is the byte-identical R17 revert.
__global__ __launch_bounds__(64, 1)
void sleep_rk4_kernel(const float* __restrict__ noise,
                      const float* __restrict__ pgRRe,
                      const float* __restrict__ pgRWe,
                      const float* __restrict__ pgWNi,
                      const float* __restrict__ pgWRi,
                      const float* __restrict__ pgNRi,
                      const float* __restrict__ pgNWi,
                      float* __restrict__ out)
{
  __shared__ float shm[16 * 128];   // [16 steps][8 regions x 16]

  const int tid  = (int)(blockIdx.x * 64u + threadIdx.x);
  const int b    = tid >> 2;        // global element
  const int bl   = b & 15;          // element within block
  const int role = tid & 3;

  const float g_RRe = *pgRRe, g_RWe = *pgRWe, g_WNi = *pgWNi;
  const float g_WRi = *pgWRi, g_NRi = *pgNRi, g_NWi = *pgNWi;

  const float L2E = 1.4426950408889634f;
  const float LN2 = 0.6931471805599453f;

  float W1, W2, W3, NSC, BB, qa, qb, pa, pb, cs, ia, ib;
  float f0, c0;
  bool role03;

  if (role == 0) {              // f_W / c_W
    const float SC = 2.0f * L2E / 0.5f;
    W1 = SC * g_NWi; W2 = SC * g_RWe; W3 = 0.0f; NSC = SC; BB = SC * 0.4f;
    qa = -1.0f / 1.5e6f; qb = 6.5f / 1.5e6f; pa = 0.0f; pb = -6.5f / 1.5e6f;
    cs = 2.0f * L2E / 5.0f; ia = -1.0f / 2.5e4f; ib = 1.0f / 2.5e4f;
    f0 = 6.0f; c0 = 0.9f; role03 = true;
  } else if (role == 1) {       // f_N / c_N
    const float SC = 2.0f * L2E / 0.175f;
    W1 = SC * g_WNi; W2 = SC * 1.5f; W3 = 0.0f; NSC = SC; BB = 0.0f;
    qa = -1.0f / 6.0e5f; qb = 5.0f / 6.0e5f; pa = 0.0f; pb = -5.0f / 6.0e5f;
    cs = 2.0f * L2E / 4.0f; ia = -1.0f / 1.0e4f; ib = 1.0f / 1.0e4f;
    f0 = 1.0e-3f; c0 = 1.0e-3f; role03 = false;
  } else if (role == 2) {       // f_R / c_R
    const float SC = 2.0f * L2E / 0.13f;
    W1 = SC * g_WRi; W2 = SC * g_NRi; W3 = SC * g_RRe; NSC = SC; BB = SC * 0.9f;
    qa = -1.0f / 6.0e4f; qb = 5.0f / 6.0e4f; pa = 0.0f; pb = -5.0f / 6.0e4f;
    cs = 2.0f * L2E / 2.0f; ia = -1.0f / 1.0e4f; ib = 1.0f / 1.0e4f;
    f0 = 1.0e-3f; c0 = 1.0e-3f; role03 = false;
  } else {                      // h (c-chain inert: stays 0, goes to trash)
    W1 = 0.0f; W2 = -5.0f * L2E; W3 = 0.0f; NSC = 0.0f; BB = 10.0f * L2E;
    qa = -1.0f / 3.06e7f; qb = 0.0f;
    pa = (1.0f / 3.06e7f - 1.0f / 3.483e7f);
    pb = 1.0f / 3.483e7f;
    cs = 0.0f; ia = 0.0f; ib = 0.0f;
    f0 = 0.5f; c0 = 0.0f; role03 = true;
  }

  const float AQAh = 0.5f * qa, AQA1 = qa;
  const float AIAh = 0.5f * ia, AIA1 = ia;
  const float IAC  = ia * cs;
  const float TIA  = 2.0f * ia;
  const float R6   = 0.16666666666666666f;

  // ---- init: closed-form step coefficients via basis runs ----
  float vF[4], vG[4];
  auto frun = [&](float f0b, float Gb, float* v) -> float {
    const float Chb = fmaf(0.5f, Gb, f0b), C1b = f0b + Gb;
    float s0 = f0b, acc = -3.0f * f0b;
    s0 = fmaf(AQAh, s0, Chb); v[0] = s0; acc = fmaf(2.0f, s0, acc);
    s0 = fmaf(AQAh, s0, Chb); v[1] = s0; acc = fmaf(4.0f, s0, acc);
    s0 = fmaf(AQA1, s0, C1b); v[2] = s0; acc = fmaf(2.0f, s0, acc);
    s0 = fmaf(AQA1, s0, C1b); v[3] = s0; acc = fmaf(1.0f, s0, acc);
    float q = acc * R6; q = fmaf(fmaf(q, -6.0f, acc), R6, q); return q;
  };
  const float KF = frun(1.0f, 0.0f, vF);
  const float KG = frun(0.0f, 1.0f, vG);

  auto crun = [&](const float* v, float c0b, float e1u, float vd1) -> float {
    const float E1h = IAC * e1u, E11 = 2.0f * IAC * e1u;
    const float Dh = c0b + 0.5f * vd1, D1 = c0b + vd1;
    float s1 = c0b, acc = -3.0f * c0b;
    s1 = fmaf(AIAh, s1, fmaf(E1h, v[0], Dh)); acc = fmaf(2.0f, s1, acc);
    s1 = fmaf(AIAh, s1, fmaf(E1h, v[1], Dh)); acc = fmaf(4.0f, s1, acc);
    s1 = fmaf(AIA1, s1, fmaf(E11, v[2], D1)); acc = fmaf(2.0f, s1, acc);
    s1 = fmaf(AIA1, s1, fmaf(E11, v[3], D1)); acc = fmaf(1.0f, s1, acc);
    float q = acc * R6; q = fmaf(fmaf(q, -6.0f, acc), R6, q); return q;
  };
  float z4[4] = {0.0f, 0.0f, 0.0f, 0.0f};
  const float KC  = crun(z4, 1.0f, 0.0f, 0.0f);
  const float LAf = crun(vF, 0.0f, 1.0f, 0.0f);
  const float LBf = crun(vG, 0.0f, 1.0f, 0.0f);
  const float KW  = crun(z4, 0.0f, 0.0f, 1.0f);

  // KG-folded constants (ulp-level identical numerics)
  const float KGi  = 1.0f / KG;
  const float LBfK = LBf * KGi;
  const float qbK  = qb * KG;

  // ---- c-sigmoid + P refresh (16-step cadence; compute/install split) ----
  float LAe, LBK, VDK, PK, tLAe, tLBK, tVDK, tPK;
  auto crefresh_compute = [&](float fcur) {
    const float zb = cs * fcur;
    const float ez = fexp2(zb);
    const float sc_ = frcp(1.0f + ez);
    const float t2 = fmaf(sc_, sc_, -sc_);
    const float e1 = LN2 * t2;
    const float vC = fmaf(-e1, zb, sc_);
    const float VD1 = fmaf(TIA, vC, ib);
    tLAe = LAf * e1; tLBK = LBfK * e1; tVDK = KW * VD1;
    tPK = fmaf(pa, fcur, pb) * KG;
  };
  crefresh_compute(f0);
  LAe = tLAe; LBK = tLBK; VDK = tVDK; PK = tPK;

  float dF = 0.0f, dC = 0.0f;
  float Gq0, Gq1, Gq2, Gq3, Gq4, Gq5, Gq6, Gq7;   // = KG * G (folded)

  // ---- LDS staging addresses (bank-conflict-free regions) ----
  const int offA = role * 16 + bl;          // f -> region[role]
  const int offB = (role + 4) * 16 + bl;    // c -> region[4+role] (r3 -> trash)

  // ---- coalesced flush setup (per-lane constants) ----
  const int  L        = (int)threadIdx.x;
  const bool fluseful = ((L & 31) < 28);
  float* gp;
  {
    const int p  = L & 31;          // unit within 32-unit step row
    const int rg = p >> 2;          // region 0..7 (7 = trash, masked)
    const int v  = (rg == 3) ? 6 : ((rg < 3) ? rg : (rg > 6 ? 0 : rg - 1));
    gp = out + (L >> 5) * 3584 + v * 512 + (p & 3) * 4 + (int)(blockIdx.x * 16u);
  }

  float nbA[16], nbB[16], nbCv[16];
#pragma unroll
  for (int j = 0; j < 16; ++j) nbA[j] = noise[b + j * BATCH];
#pragma unroll
  for (int j = 0; j < 16; ++j) nbB[j] = noise[b + (16 + j) * BATCH];

  // ---- prefill: GK for steps 0..7 (frozen state, zero slope) ----
  {
    const float pubS = role03 ? f0 : c0;
    const float xAs = qperm<0x01>(c0);
    const float xBs = qperm<0x1E>(pubS);
    const float YB = fmaf(W1, xAs, fmaf(W2, xBs, fmaf(W3, c0, BB)));
    Gq0 = fmaf(PK, frcp(1.0f + fexp2(fmaf(NSC, nbA[0], YB))), qbK);
    Gq1 = fmaf(PK, frcp(1.0f + fexp2(fmaf(NSC, nbA[1], YB))), qbK);
    Gq2 = fmaf(PK, frcp(1.0f + fexp2(fmaf(NSC, nbA[2], YB))), qbK);
    Gq3 = fmaf(PK, frcp(1.0f + fexp2(fmaf(NSC, nbA[3], YB))), qbK);
    Gq4 = fmaf(PK, frcp(1.0f + fexp2(fmaf(NSC, nbA[4], YB))), qbK);
    Gq5 = fmaf(PK, frcp(1.0f + fexp2(fmaf(NSC, nbA[5], YB))), qbK);
    Gq6 = fmaf(PK, frcp(1.0f + fexp2(fmaf(NSC, nbA[6], YB))), qbK);
    Gq7 = fmaf(PK, frcp(1.0f + fexp2(fmaf(NSC, nbA[7], YB))), qbK);
  }

  // One 8-step group at step-slot SJ: consumes Gq0..7, computes next
  // group's GK batch (EXT = 8.5..15.5), 8 step-maps, stages to LDS.
  auto GROUP8 = [&](int SJ, float n0, float n1, float n2, float n3,
                    float n4, float n5, float n6, float n7) {
    const float pubS = role03 ? f0 : c0;
    const float pubD = role03 ? dF : dC;
    const float xAs = qperm<0x01>(c0);
    const float xBs = qperm<0x1E>(pubS);
    const float xAd = qperm<0x01>(dC);
    const float xBd = qperm<0x1E>(pubD);
    float YB = fmaf(W3, c0, BB);
    float dY = W3 * dC;
    const float f1 = fmaf(KF, f0, Gq0);
    const float c1 = fmaf(KC, c0, fmaf(LAe, f0, fmaf(LBK, Gq0, VDK)));
    YB = fmaf(W2, xBs, YB);
    dY = fmaf(W2, xBd, dY);
    const float f2 = fmaf(KF, f1, Gq1);
    const float c2 = fmaf(KC, c1, fmaf(LAe, f1, fmaf(LBK, Gq1, VDK)));
    YB = fmaf(W1, xAs, YB);
    dY = fmaf(W1, xAd, dY);
    const float f3 = fmaf(KF, f2, Gq2);
    const float c3 = fmaf(KC, c2, fmaf(LAe, f2, fmaf(LBK, Gq2, VDK)));
    const float y0 = fmaf(NSC, n0, fmaf( 8.5f, dY, YB));
    const float y1 = fmaf(NSC, n1, fmaf( 9.5f, dY, YB));
    const float y2 = fmaf(NSC, n2, fmaf(10.5f, dY, YB));
    const float y3 = fmaf(NSC, n3, fmaf(11.5f, dY, YB));
    const float f4 = fmaf(KF, f3, Gq3);
    const float c4 = fmaf(KC, c3, fmaf(LAe, f3, fmaf(LBK, Gq3, VDK)));
    const float y4 = fmaf(NSC, n4, fmaf(12.5f, dY, YB));
    const float y5 = fmaf(NSC, n5, fmaf(13.5f, dY, YB));
    const float y6 = fmaf(NSC, n6, fmaf(14.5f, dY, YB));
    const float y7 = fmaf(NSC, n7, fmaf(15.5f, dY, YB));
    const float e0 = fexp2(y0);
    const float e1_ = fexp2(y1);
    const float f5 = fmaf(KF, f4, Gq4);
    const float c5 = fmaf(KC, c4, fmaf(LAe, f4, fmaf(LBK, Gq4, VDK)));
    const float e2 = fexp2(y2);
    const float e3 = fexp2(y3);
    const float f6 = fmaf(KF, f5, Gq5);
    const float c6 = fmaf(KC, c5, fmaf(LAe, f5, fmaf(LBK, Gq5, VDK)));
    const float e4 = fexp2(y4);
    const float e5 = fexp2(y5);
    const float f7 = fmaf(KF, f6, Gq6);
    const float c7 = fmaf(KC, c6, fmaf(LAe, f6, fmaf(LBK, Gq6, VDK)));
    const float e6 = fexp2(y6);
    const float e7 = fexp2(y7);
    const float f8 = fmaf(KF, f7, Gq7);
    const float c8 = fmaf(KC, c7, fmaf(LAe, f7, fmaf(LBK, Gq7, VDK)));
    const float r0 = frcp(1.0f + e0);
    const float r1 = frcp(1.0f + e1_);
    const float r2 = frcp(1.0f + e2);
    const float r3 = frcp(1.0f + e3);
    const float r4 = frcp(1.0f + e4);
    const float r5 = frcp(1.0f + e5);
    const float r6 = frcp(1.0f + e6);
    const float r7 = frcp(1.0f + e7);
    shm[(SJ + 0) * 128 + offA] = f1;  shm[(SJ + 0) * 128 + offB] = c1;
    shm[(SJ + 1) * 128 + offA] = f2;  shm[(SJ + 1) * 128 + offB] = c2;
    shm[(SJ + 2) * 128 + offA] = f3;  shm[(SJ + 2) * 128 + offB] = c3;
    shm[(SJ + 3) * 128 + offA] = f4;  shm[(SJ + 3) * 128 + offB] = c4;
    shm[(SJ + 4) * 128 + offA] = f5;  shm[(SJ + 4) * 128 + offB] = c5;
    shm[(SJ + 5) * 128 + offA] = f6;  shm[(SJ + 5) * 128 + offB] = c6;
    shm[(SJ + 6) * 128 + offA] = f7;  shm[(SJ + 6) * 128 + offB] = c7;
    shm[(SJ + 7) * 128 + offA] = f8;  shm[(SJ + 7) * 128 + offB] = c8;
    Gq0 = fmaf(PK, r0, qbK);
    Gq1 = fmaf(PK, r1, qbK);
    Gq2 = fmaf(PK, r2, qbK);
    Gq3 = fmaf(PK, r3, qbK);
    Gq4 = fmaf(PK, r4, qbK);
    Gq5 = fmaf(PK, r5, qbK);
    Gq6 = fmaf(PK, r6, qbK);
    Gq7 = fmaf(PK, r7, qbK);
    dF = f8 - f7; dC = c8 - c7;
    f0 = f8; c0 = c8;
  };

  int base = 0;

  // 16-step block, TRIPLE buffered: consumes nb1_[8..15] (loaded 2 blocks
  // ago) and nb2_[0..7] (loaded 1 block ago); loads nbL_ for block+2.
  // vmcnt at pins: nb2_ = 24 ops after its loads, nb1_ = 48 -> encodable.
#define TBLOCK(nb1_, nb2_, nbL_)                                              \
  do {                                                                        \
    int tl = base + 32; if (tl > T_STEPS - 16) tl = T_STEPS - 16;             \
    const float* __restrict__ lp = noise + (size_t)tl * BATCH;                \
    _Pragma("unroll")                                                         \
    for (int j = 0; j < 16; ++j) nbL_[j] = lp[b + j * BATCH];                 \
    _Pragma("unroll")                                                         \
    for (int j = 8; j < 16; ++j) PIN(nb1_[j]);                                \
    _Pragma("unroll")                                                         \
    for (int j = 0; j < 8; ++j) PIN(nb2_[j]);                                 \
    crefresh_compute(f0);                                                     \
    GROUP8(0, nb1_[8], nb1_[9], nb1_[10], nb1_[11],                           \
              nb1_[12], nb1_[13], nb1_[14], nb1_[15]);                        \
    LAe = tLAe; LBK = tLBK; VDK = tVDK; PK = tPK;                             \
    GROUP8(8, nb2_[0], nb2_[1], nb2_[2], nb2_[3],                             \
              nb2_[4], nb2_[5], nb2_[6], nb2_[7]);                            \
    if (fluseful) {                                                           \
      _Pragma("unroll")                                                       \
      for (int r = 0; r < 8; ++r) {                                           \
        const float4 vv = *(const float4*)&shm[L * 4 + r * 256];              \
        *(float4*)gp = vv;                                                    \
        gp += 7168;                                                           \
      }                                                                       \
    }                                                                         \
    base += 16;                                                               \
  } while (0)

  // 625 blocks = 208 triples + 1 tail.
  for (int kk = 0; kk < 208; ++kk) {
    TBLOCK(nbA, nbB, nbCv);
    TBLOCK(nbB, nbCv, nbA);
    TBLOCK(nbCv, nbA, nbB);
  }
  TBLOCK(nbA, nbB, nbCv);   // block 624 (tail G reads clamped, unused)
#undef TBLOCK
}

extern "C" void kernel_launch(void* const* d_in, const int* in_sizes, int n_in,
                              void* d_out, int out_size, void* d_ws, size_t ws_size,
                              hipStream_t stream) {
  const float* noise = (const float*)d_in[0];
  const float* gRRe  = (const float*)d_in[1];
  const float* gRWe  = (const float*)d_in[2];
  const float* gWNi  = (const float*)d_in[3];
  const float* gWRi  = (const float*)d_in[4];
  const float* gNRi  = (const float*)d_in[5];
  const float* gNWi  = (const float*)d_in[6];
  float* out = (float*)d_out;

  // 32 blocks x 64 threads -> 1 wave/CU on 32 CUs (max TLP for B=512@4 lanes).
  sleep_rk4_kernel<<<dim3((BATCH * 4) / 64), dim3(64), 0, stream>>>(
      noise, gRRe, gRWe, gWNi, gWRi, gNRi, gNWi, out);
}